// Round 2
// baseline (224.149 us; speedup 1.0000x reference)
//
#include <hip/hip_runtime.h>
#include <hip/hip_bf16.h>

#define N_ 2048
#define D_ 128
#define B_ 8
#define BM 128
#define BK 64
#define JSPLIT 8
#define JCHUNK (N_ / JSPLIT)   // 256
#define NBLOCKS (B_ * 16 * JSPLIT)  // 1024

typedef __attribute__((ext_vector_type(8))) short short8;
typedef __attribute__((ext_vector_type(4))) float f32x4;
typedef __attribute__((ext_vector_type(4))) unsigned short ushort4v;

__device__ __forceinline__ unsigned short f2bf(float x) {
  unsigned int u = __builtin_bit_cast(unsigned int, x);
  u += 0x7fffu + ((u >> 16) & 1u);   // RNE; finite inputs
  return (unsigned short)(u >> 16);
}

__device__ __forceinline__ void async_lds16(const void* g, void* l) {
  __builtin_amdgcn_global_load_lds(
      (const __attribute__((address_space(1))) void*)g,
      (__attribute__((address_space(3))) void*)l, 16, 0, 0);
}

// Build VT[b][128][2048] = bf16(emb^T) and hsq[b][2048] fp32. Block = 64 nodes.
__global__ __launch_bounds__(256) void prep_kernel(
    const float* __restrict__ emb, unsigned short* __restrict__ vt,
    float* __restrict__ hsq) {
  __shared__ float semb[64 * 132];   // stride 132: float4-aligned stores
  __shared__ float shsq[64];
  const int t = threadIdx.x;
  const int bb = blockIdx.x >> 5;
  const int j0 = (blockIdx.x & 31) << 6;
  const float* ebase = emb + ((size_t)(bb * N_ + j0)) * D_;
#pragma unroll
  for (int it = 0; it < 8; ++it) {
    int fidx = it * 1024 + t * 4;
    int j = fidx >> 7, d = fidx & 127;
    const float4 v = *(const float4*)(ebase + (size_t)j * D_ + d);
    *(float4*)&semb[j * 132 + d] = v;
  }
  __syncthreads();
  {
    int j = t >> 2, q = t & 3;
    const float* row = &semb[j * 132 + q * 32];
    float p = 0.f;
#pragma unroll
    for (int x = 0; x < 32; ++x) p += row[x] * row[x];
    p += __shfl_down(p, 2);
    p += __shfl_down(p, 1);
    if (q == 0) { shsq[j] = p; hsq[bb * N_ + j0 + j] = p; }
  }
  __syncthreads();
  // 128 d-rows x 8 short8-units each = 1024 units over 256 threads = 4 iters,
  // 16B stores, 1 KB contiguous per 8 lanes of a d-row group.
  unsigned short* vbase = vt + (size_t)bb * D_ * N_ + j0;
#pragma unroll
  for (int it = 0; it < 4; ++it) {
    int idx = it * 256 + t;
    int d = idx >> 3, jg = idx & 7;
    short8 o;
#pragma unroll
    for (int x = 0; x < 8; ++x)
      o[x] = (short)f2bf(semb[(jg * 8 + x) * 132 + d]);
    *(short8*)&vbase[(size_t)d * N_ + jg * 8] = o;
  }
}

// Per block: cross-term tile (A @ V^T) dot U via MFMA + exact fp32 hsq-terms
// accumulated during A staging. b = bid&7 -> XCD-pinned batch (L2 locality).
__global__ __launch_bounds__(256, 4) void gemm_kernel(
    const float* __restrict__ adj, const float* __restrict__ emb,
    const float* __restrict__ hsq, const unsigned short* __restrict__ vt,
    float* __restrict__ partials) {
  __shared__ unsigned short lA[BM * 72];     // [row][64] pad->72 (144 B stride)
  __shared__ unsigned short lV[128 * 64];    // [d][64], 16B-unit XOR swizzle on d&7
  __shared__ float red[4];

  const int t = threadIdx.x;
  const int lane = t & 63, wave = t >> 6;
  const int lhalf = lane & 15, quad = lane >> 4;
  const int bid = blockIdx.x;
  const int b = bid & 7;                     // bid%8 ~ XCD id
  const int rem = bid >> 3;
  const int i0 = (rem & 15) << 7;            // 16 i-tiles of 128
  const int j0 = (rem >> 4) * JCHUNK;        // 8 j-chunks of 256

  const float* abase = adj + ((size_t)b << 22);
  const unsigned short* vtbase = vt + (size_t)b * D_ * N_;
  const float* embb = emb + (size_t)b * N_ * D_;
  const float* hsqb = hsq + b * N_;

  f32x4 acc[2][8] = {};
  const int col = (t << 2) & 63;             // fixed 4 cols per thread
  float hsqi[8];
#pragma unroll
  for (int it = 0; it < 8; ++it) hsqi[it] = hsqb[i0 + it * 16 + (t >> 4)];
  float p1 = 0.f, p2 = 0.f;

  for (int ki = 0; ki < JCHUNK / BK; ++ki) {
    const int jk = j0 + ki * BK;
    // VT tile: 128 rows x 64 cols bf16 = 1024 16B units, direct-to-LDS.
    // XOR swizzle realized in the per-lane GLOBAL source address.
#pragma unroll
    for (int it = 0; it < 4; ++it) {
      int flat = it * 256 + t;
      int r = flat >> 3, up = flat & 7;
      int ul = up ^ (r & 7);
      async_lds16(vtbase + (size_t)r * N_ + jk + ul * 8,
                  (char*)lV + (size_t)flat * 16);
    }
    const float4 hj = *(const float4*)&hsqb[jk + col];
    // A tile 128x64 fp32 -> bf16 LDS; fold exact hsq-terms while data is in regs.
#pragma unroll
    for (int half = 0; half < 2; ++half) {
      float4 va[4];
#pragma unroll
      for (int q = 0; q < 4; ++q) {
        int row = (half * 4 + q) * 16 + (t >> 4);
        va[q] = *(const float4*)(abase + (size_t)(i0 + row) * N_ + jk + col);
      }
#pragma unroll
      for (int q = 0; q < 4; ++q) {
        int it = half * 4 + q;
        int row = it * 16 + (t >> 4);
        ushort4v pk;
        pk.x = f2bf(va[q].x); pk.y = f2bf(va[q].y);
        pk.z = f2bf(va[q].z); pk.w = f2bf(va[q].w);
        *(ushort4v*)&lA[row * 72 + col] = pk;
        p1 += (va[q].x + va[q].y + va[q].z + va[q].w) * hsqi[it];
        p2 += va[q].x * hj.x + va[q].y * hj.y + va[q].z * hj.z + va[q].w * hj.w;
      }
    }
    __syncthreads();
#pragma unroll
    for (int ks = 0; ks < 2; ++ks) {
      const int krow = ks * 32 + quad * 8;
      short8 a0 = *(const short8*)&lA[(wave * 32 + lhalf) * 72 + krow];
      short8 a1 = *(const short8*)&lA[(wave * 32 + 16 + lhalf) * 72 + krow];
#pragma unroll
      for (int nt = 0; nt < 8; ++nt) {
        int r = nt * 16 + lhalf;
        int up = (ks * 4 + quad) ^ (r & 7);
        short8 bfrag = *(const short8*)&lV[r * 64 + up * 8];
        acc[0][nt] = __builtin_amdgcn_mfma_f32_16x16x32_bf16(a0, bfrag, acc[0][nt], 0, 0, 0);
        acc[1][nt] = __builtin_amdgcn_mfma_f32_16x16x32_bf16(a1, bfrag, acc[1][nt], 0, 0, 0);
      }
    }
    __syncthreads();
  }

  // cross-term epilogue: C/D layout col=lane&15, row=quad*4+reg
  float pc = 0.f;
#pragma unroll
  for (int mt = 0; mt < 2; ++mt) {
#pragma unroll
    for (int r = 0; r < 4; ++r) {
      int i = i0 + wave * 32 + mt * 16 + quad * 4 + r;
      const float* erow = embb + (size_t)i * D_;
#pragma unroll
      for (int nt = 0; nt < 8; ++nt)
        pc += acc[mt][nt][r] * erow[nt * 16 + lhalf];
    }
  }
  float part = p1 + p2 - 2.0f * pc;
#pragma unroll
  for (int off = 32; off > 0; off >>= 1) part += __shfl_down(part, off);
  if (lane == 0) red[wave] = part;
  __syncthreads();
  if (t == 0) partials[bid] = red[0] + red[1] + red[2] + red[3];
}

__global__ void finish_kernel(const float* __restrict__ partials,
                              float* __restrict__ out) {
  double s = 0.0;
  int t = threadIdx.x;
  for (int i = t; i < NBLOCKS; i += 64) s += (double)partials[i];
#pragma unroll
  for (int off = 32; off > 0; off >>= 1) s += __shfl_down(s, off);
  if (t == 0) out[0] = (float)(s / (double)((size_t)B_ * N_));
}

extern "C" void kernel_launch(void* const* d_in, const int* in_sizes, int n_in,
                              void* d_out, int out_size, void* d_ws, size_t ws_size,
                              hipStream_t stream) {
  const float* adj = (const float*)d_in[0];
  const float* emb = (const float*)d_in[1];
  // ws: hsq (64 KiB) | VT bf16 (4 MiB) | partials (4 KiB)
  float* hsq = (float*)d_ws;
  unsigned short* vt = (unsigned short*)((char*)d_ws + 65536);
  float* partials = (float*)((char*)d_ws + 65536 + (size_t)B_ * D_ * N_ * 2);

  prep_kernel<<<B_ * (N_ / 64), 256, 0, stream>>>(emb, vt, hsq);
  gemm_kernel<<<NBLOCKS, 256, 0, stream>>>(adj, emb, hsq, vt, partials);
  finish_kernel<<<1, 64, 0, stream>>>(partials, (float*)d_out);
}

// Round 3
// 211.151 us; speedup vs baseline: 1.0616x; 1.0616x over previous
//
#include <hip/hip_runtime.h>
#include <hip/hip_bf16.h>

#define N_ 2048
#define D_ 128
#define B_ 8
#define BM 64
#define BK 64
#define JSPLIT 4
#define JCHUNK (N_ / JSPLIT)            // 512 -> 8 K-steps
#define NSTEPS (JCHUNK / BK)            // 8
#define NBLOCKS (B_ * (N_ / BM) * JSPLIT)  // 1024 = 4 blocks/CU exact

typedef __attribute__((ext_vector_type(8))) short short8;
typedef __attribute__((ext_vector_type(4))) float f32x4;

__device__ __forceinline__ unsigned short f2bf(float x) {
  unsigned int u = __builtin_bit_cast(unsigned int, x);
  u += 0x7fffu + ((u >> 16) & 1u);   // RNE; finite inputs
  return (unsigned short)(u >> 16);
}

__device__ __forceinline__ void async_lds16(const void* g, void* l) {
  __builtin_amdgcn_global_load_lds(
      (const __attribute__((address_space(1))) void*)g,
      (__attribute__((address_space(3))) void*)l, 16, 0, 0);
}

__device__ __forceinline__ short8 pack8(float4 a, float4 b) {
  short8 o;
  o[0] = (short)f2bf(a.x); o[1] = (short)f2bf(a.y);
  o[2] = (short)f2bf(a.z); o[3] = (short)f2bf(a.w);
  o[4] = (short)f2bf(b.x); o[5] = (short)f2bf(b.y);
  o[6] = (short)f2bf(b.z); o[7] = (short)f2bf(b.w);
  return o;
}

// Build VT[b][128][2048] = bf16(emb^T) and hsq[b][2048] fp32. Block = 64 nodes.
__global__ __launch_bounds__(256) void prep_kernel(
    const float* __restrict__ emb, unsigned short* __restrict__ vt,
    float* __restrict__ hsq) {
  __shared__ float semb[64 * 132];
  __shared__ float shsq[64];
  const int t = threadIdx.x;
  const int bb = blockIdx.x >> 5;
  const int j0 = (blockIdx.x & 31) << 6;
  const float* ebase = emb + ((size_t)(bb * N_ + j0)) * D_;
#pragma unroll
  for (int it = 0; it < 8; ++it) {
    int fidx = it * 1024 + t * 4;
    int j = fidx >> 7, d = fidx & 127;
    const float4 v = *(const float4*)(ebase + (size_t)j * D_ + d);
    *(float4*)&semb[j * 132 + d] = v;
  }
  __syncthreads();
  {
    int j = t >> 2, q = t & 3;
    const float* row = &semb[j * 132 + q * 32];
    float p = 0.f;
#pragma unroll
    for (int x = 0; x < 32; ++x) p += row[x] * row[x];
    p += __shfl_down(p, 2);
    p += __shfl_down(p, 1);
    if (q == 0) { shsq[j] = p; hsq[bb * N_ + j0 + j] = p; }
  }
  __syncthreads();
  unsigned short* vbase = vt + (size_t)bb * D_ * N_ + j0;
#pragma unroll
  for (int it = 0; it < 4; ++it) {
    int idx = it * 256 + t;
    int d = idx >> 3, jg = idx & 7;
    short8 o;
#pragma unroll
    for (int x = 0; x < 8; ++x)
      o[x] = (short)f2bf(semb[(jg * 8 + x) * 132 + d]);
    *(short8*)&vbase[(size_t)d * N_ + jg * 8] = o;
  }
}

// Per block: 64 i-rows x 512 j-chunk. A-fragments loaded GLOBAL->REG directly
// (no LDS staging, no staging barrier); V double-buffered in LDS via
// global_load_lds with ONE barrier per K-step whose vmcnt drain only waits
// L2-hot V prefetches issued a full A-phase earlier.
__global__ __launch_bounds__(256, 4) void gemm_kernel(
    const float* __restrict__ adj, const float* __restrict__ emb,
    const float* __restrict__ hsq, const unsigned short* __restrict__ vt,
    float* __restrict__ partials) {
  __shared__ unsigned short lV[2][128 * 64];  // [d][64], 16B-unit XOR swizzle on d&7
  __shared__ float red[4];

  const int t = threadIdx.x;
  const int lane = t & 63, wave = t >> 6;
  const int lhalf = lane & 15, quad = lane >> 4;
  const int bid = blockIdx.x;
  const int b = bid & 7;                      // XCD-pinned batch
  const int rem = bid >> 3;
  const int i0 = (rem & 31) << 6;             // 32 i-tiles of 64
  const int j0 = (rem >> 5) * JCHUNK;         // 4 j-chunks of 512

  const unsigned short* vtbase = vt + (size_t)b * D_ * N_;
  const float* embb = emb + (size_t)b * N_ * D_;
  const float* hsqb = hsq + b * N_;
  const int irow = i0 + wave * 16 + lhalf;    // this lane's A row (m = lhalf)
  const float* arow = adj + ((size_t)b << 22) + (size_t)irow * N_;
  const float hsqi = hsqb[irow];

  f32x4 acc[8] = {};
  float p1 = 0.f, p2 = 0.f;

  auto loadV = [&](int jk, int sel) {
#pragma unroll
    for (int it = 0; it < 4; ++it) {
      int flat = it * 256 + t;
      int r = flat >> 3, up = flat & 7;
      int ul = up ^ (r & 7);
      async_lds16(vtbase + (size_t)r * N_ + jk + ul * 8,
                  (char*)lV[sel] + (size_t)flat * 16);
    }
  };

  loadV(j0, 0);
  __syncthreads();

  for (int ki = 0; ki < NSTEPS; ++ki) {
    const int cur = ki & 1;
    const int jk = j0 + ki * BK;
    if (ki < NSTEPS - 1) loadV(jk + BK, cur ^ 1);   // prefetch next V tile

    // --- A fragments direct from global: k = ks*32 + quad*8 + x
    const float* ap = arow + jk + quad * 8;
    float4 va0 = *(const float4*)ap;
    float4 va1 = *(const float4*)(ap + 4);
    float4 va2 = *(const float4*)(ap + 32);
    float4 va3 = *(const float4*)(ap + 36);
    const float4 h0 = *(const float4*)(hsqb + jk + quad * 8);
    const float4 h1 = *(const float4*)(hsqb + jk + quad * 8 + 4);
    const float4 h2 = *(const float4*)(hsqb + jk + quad * 8 + 32);
    const float4 h3 = *(const float4*)(hsqb + jk + quad * 8 + 36);

    float s = (va0.x + va0.y + va0.z + va0.w) + (va1.x + va1.y + va1.z + va1.w)
            + (va2.x + va2.y + va2.z + va2.w) + (va3.x + va3.y + va3.z + va3.w);
    p1 += s * hsqi;
    p2 += va0.x*h0.x + va0.y*h0.y + va0.z*h0.z + va0.w*h0.w
        + va1.x*h1.x + va1.y*h1.y + va1.z*h1.z + va1.w*h1.w
        + va2.x*h2.x + va2.y*h2.y + va2.z*h2.z + va2.w*h2.w
        + va3.x*h3.x + va3.y*h3.y + va3.z*h3.z + va3.w*h3.w;

    short8 f0 = pack8(va0, va1);   // ks=0
    short8 f1 = pack8(va2, va3);   // ks=1

    // --- MFMA against V tile in LDS (swizzled)
#pragma unroll
    for (int nt = 0; nt < 8; ++nt) {
      int r = nt * 16 + lhalf;
      short8 b0 = *(const short8*)((char*)lV[cur] + (size_t)(r * 8 + (quad ^ (r & 7))) * 16);
      short8 b1 = *(const short8*)((char*)lV[cur] + (size_t)(r * 8 + ((4 + quad) ^ (r & 7))) * 16);
      acc[nt] = __builtin_amdgcn_mfma_f32_16x16x32_bf16(f0, b0, acc[nt], 0, 0, 0);
      acc[nt] = __builtin_amdgcn_mfma_f32_16x16x32_bf16(f1, b1, acc[nt], 0, 0, 0);
    }
    __syncthreads();   // drains V prefetch (issued ~full A-phase ago, L2-hot)
  }

  // --- epilogue: C/D layout col=lane&15 (d), row=quad*4+reg (i)
  float pc = 0.f;
#pragma unroll
  for (int r = 0; r < 4; ++r) {
    int i = i0 + wave * 16 + quad * 4 + r;
    const float* erow = embb + (size_t)i * D_;
#pragma unroll
    for (int nt = 0; nt < 8; ++nt)
      pc += acc[nt][r] * erow[nt * 16 + lhalf];
  }
  float part = p1 + p2 - 2.0f * pc;
#pragma unroll
  for (int off = 32; off > 0; off >>= 1) part += __shfl_down(part, off);
  if (lane == 0) red[wave] = part;
  __syncthreads();
  if (t == 0) partials[bid] = red[0] + red[1] + red[2] + red[3];
}

__global__ void finish_kernel(const float* __restrict__ partials,
                              float* __restrict__ out) {
  double s = 0.0;
  int t = threadIdx.x;
  for (int i = t; i < NBLOCKS; i += 64) s += (double)partials[i];
#pragma unroll
  for (int off = 32; off > 0; off >>= 1) s += __shfl_down(s, off);
  if (t == 0) out[0] = (float)(s / (double)((size_t)B_ * N_));
}

extern "C" void kernel_launch(void* const* d_in, const int* in_sizes, int n_in,
                              void* d_out, int out_size, void* d_ws, size_t ws_size,
                              hipStream_t stream) {
  const float* adj = (const float*)d_in[0];
  const float* emb = (const float*)d_in[1];
  // ws: hsq (64 KiB) | VT bf16 (4 MiB) | partials (4 KiB)
  float* hsq = (float*)d_ws;
  unsigned short* vt = (unsigned short*)((char*)d_ws + 65536);
  float* partials = (float*)((char*)d_ws + 65536 + (size_t)B_ * D_ * N_ * 2);

  prep_kernel<<<B_ * (N_ / 64), 256, 0, stream>>>(emb, vt, hsq);
  gemm_kernel<<<NBLOCKS, 256, 0, stream>>>(adj, emb, hsq, vt, partials);
  finish_kernel<<<1, 64, 0, stream>>>(partials, (float*)d_out);
}